// Round 3
// baseline (315.561 us; speedup 1.0000x reference)
//
#include <hip/hip_runtime.h>

#define T_LEN 1024
#define N_DIM 256
#define EPL 4  // elements per lane per batch (256 / 64)

typedef float f2 __attribute__((ext_vector_type(2)));

// Wave64 reduction level via DPP (VALU pipe; fused v_add with DPP src).
template<int CTRL>
__device__ __forceinline__ float dpp_add_f32(float v) {
    int mv = __builtin_amdgcn_update_dpp(0, __float_as_int(v), CTRL, 0xf, 0xf, true);
    return v + __int_as_float(mv);
}
// Full 6-level wave64 sum; total lands in lane 63.
__device__ __forceinline__ float wave_red(float p) {
    p = dpp_add_f32<0x111>(p);  // row_shr:1
    p = dpp_add_f32<0x112>(p);  // row_shr:2
    p = dpp_add_f32<0x114>(p);  // row_shr:4
    p = dpp_add_f32<0x118>(p);  // row_shr:8
    p = dpp_add_f32<0x142>(p);  // row_bcast:15
    p = dpp_add_f32<0x143>(p);  // row_bcast:31
    return p;
}
__device__ __forceinline__ float rdl63(float p) {
    return __int_as_float(__builtin_amdgcn_readlane(__float_as_int(p), 63));
}

// One wave (64 lanes) per block; each wave runs TWO independent batch
// recurrences packed as float2 (.x = batch 2b, .y = batch 2b+1) so the
// elementwise work lowers to v_pk_*_f32 and the two dependency chains
// interleave to fill stall cycles (1 wave/SIMD -> no TLP available).
__global__ __launch_bounds__(64, 1) void rnn_lowrank_kernel(
    const float* __restrict__ u,   // (B, T)
    const float* __restrict__ m,   // (N, 2) row-major
    const float* __restrict__ n,   // (N, 2) row-major
    const float* __restrict__ wi,  // (N,)
    const float* __restrict__ w,   // (N, 1)
    float* __restrict__ z)         // (B, T)
{
    __shared__ f2 u2_lds[T_LEN];   // (dt*uA[t], dt*uB[t]) interleaved, 8 KB

    const int lane = threadIdx.x;  // 0..63
    const int bA   = blockIdx.x << 1;
    const int bB   = bA + 1;

    const float dt   = 0.2f;
    const float invN = 1.0f / (float)N_DIM;
    const float c    = 2.8853900817779268f;  // 2*log2(e): track y = c*x

    // ---- stage u rows for both batches, pre-scaled by dt, as interleaved f2 ----
    {
        const float4* sA = reinterpret_cast<const float4*>(u + (size_t)bA * T_LEN);
        const float4* sB = reinterpret_cast<const float4*>(u + (size_t)bB * T_LEN);
#pragma unroll
        for (int k = 0; k < 4; ++k) {
            float4 a = sA[lane + (k << 6)];
            float4 b = sB[lane + (k << 6)];
            int base = (lane + (k << 6)) << 2;
            u2_lds[base + 0] = (f2){a.x * dt, b.x * dt};
            u2_lds[base + 1] = (f2){a.y * dt, b.y * dt};
            u2_lds[base + 2] = (f2){a.z * dt, b.z * dt};
            u2_lds[base + 3] = (f2){a.w * dt, b.w * dt};
        }
    }
    __syncthreads();

    // ---- weights (SHARED by both batches) as f2 splats for pk ops ----
    // Basis: y_t = A*(c*m0) + B*(c*m1) + G*(c*wi), with
    //   A' = 0.8A + a0   (a0 = sum r * n0*(dt/N) -- dt/N folded into n0r)
    //   B' = 0.8B + a1
    //   G' = 0.8G + dt*u_t                (dt folded at staging)
    //   r  = tanh(x) = 1 - 2/(exp2(y)+1)
    //   z_t = sum r * (w/N)
    f2 m0f2[EPL], m1f2[EPL], wif2[EPL], n0r2[EPL], n1r2[EPL], wf2[EPL];
#pragma unroll
    for (int e = 0; e < EPL; ++e) {
        int j = lane + (e << 6);
        float m0v = m[2 * j + 0] * c;
        float m1v = m[2 * j + 1] * c;
        float wiv = wi[j] * c;
        float n0v = n[2 * j + 0] * (dt * invN);
        float n1v = n[2 * j + 1] * (dt * invN);
        float wv  = w[j] * invN;
        m0f2[e] = (f2){m0v, m0v};
        m1f2[e] = (f2){m1v, m1v};
        wif2[e] = (f2){wiv, wiv};
        n0r2[e] = (f2){n0v, n0v};
        n1r2[e] = (f2){n1v, n1v};
        wf2[e]  = (f2){wv,  wv};
    }

    f2 A2 = (f2){0.0f, 0.0f}, B2 = (f2){0.0f, 0.0f}, G2 = (f2){0.0f, 0.0f};
    f2 a02 = (f2){0.0f, 0.0f}, a12 = (f2){0.0f, 0.0f};  // reductions from prev step
    const f2 decay2 = (f2){0.8f, 0.8f};

    float zbufA = 0.0f, zbufB = 0.0f;
    f2 u_cur = u2_lds[0];

    for (int t = 0; t < T_LEN; ++t) {
        // prefetch next u pair (broadcast ds_read_b64; wraps harmlessly at end)
        f2 u_next = u2_lds[(t + 1) & (T_LEN - 1)];

        // scalar-state updates (3 pk fma): coefficients of x_{t+1}
        A2 = __builtin_elementwise_fma(A2, decay2, a02);
        B2 = __builtin_elementwise_fma(B2, decay2, a12);
        G2 = __builtin_elementwise_fma(G2, decay2, u_cur);

        f2 p0 = (f2){0.0f, 0.0f}, p1 = (f2){0.0f, 0.0f}, pz = (f2){0.0f, 0.0f};
#pragma unroll
        for (int e = 0; e < EPL; ++e) {
            f2 y = A2 * m0f2[e];
            y = __builtin_elementwise_fma(B2, m1f2[e], y);
            y = __builtin_elementwise_fma(G2, wif2[e], y);
            f2 ex;
            ex.x = __builtin_amdgcn_exp2f(y.x);
            ex.y = __builtin_amdgcn_exp2f(y.y);
            f2 den = ex + 1.0f;
            f2 rc;
            rc.x = __builtin_amdgcn_rcpf(den.x);
            rc.y = __builtin_amdgcn_rcpf(den.y);
            f2 r = __builtin_elementwise_fma((f2){-2.0f, -2.0f}, rc, (f2){1.0f, 1.0f});
            p0 = __builtin_elementwise_fma(r, n0r2[e], p0);
            p1 = __builtin_elementwise_fma(r, n1r2[e], p1);
            pz = __builtin_elementwise_fma(r, wf2[e], pz);
        }

        // 6 interleaved wave64 DPP trees (3 per batch)
        float s00 = wave_red(p0.x), s01 = wave_red(p0.y);
        float s10 = wave_red(p1.x), s11 = wave_red(p1.y);
        float sz0 = wave_red(pz.x), sz1 = wave_red(pz.y);

        a02 = (f2){rdl63(s00), rdl63(s01)};
        a12 = (f2){rdl63(s10), rdl63(s11)};
        float zsA = rdl63(sz0);
        float zsB = rdl63(sz1);

        // capture z_t on lane (t mod 64); coalesced 64-wide stores every 64 steps
        bool cap = (lane == (t & 63));
        zbufA = cap ? zsA : zbufA;
        zbufB = cap ? zsB : zbufB;
        if ((t & 63) == 63) {
            z[(size_t)bA * T_LEN + (t - 63) + lane] = zbufA;
            z[(size_t)bB * T_LEN + (t - 63) + lane] = zbufB;
        }

        u_cur = u_next;
    }
}

extern "C" void kernel_launch(void* const* d_in, const int* in_sizes, int n_in,
                              void* d_out, int out_size, void* d_ws, size_t ws_size,
                              hipStream_t stream) {
    const float* u  = (const float*)d_in[0];
    const float* m  = (const float*)d_in[1];
    const float* n  = (const float*)d_in[2];
    const float* wi = (const float*)d_in[3];
    const float* w  = (const float*)d_in[4];
    float* z = (float*)d_out;

    // 512 one-wave blocks, 2 batches per wave
    dim3 grid(512), block(64);
    hipLaunchKernelGGL(rnn_lowrank_kernel, grid, block, 0, stream, u, m, n, wi, w, z);
}

// Round 6
// 204.678 us; speedup vs baseline: 1.5417x; 1.5417x over previous
//
#include <hip/hip_runtime.h>

#define T_LEN 1024

typedef float f2 __attribute__((ext_vector_type(2)));

__device__ __forceinline__ f2 sp(float x) { return (f2){x, x}; }

// Wave64 reduction level via DPP (mov_dpp + add; combiner fuses to v_add_f32_dpp).
template<int CTRL>
__device__ __forceinline__ float dpp_add_f32(float v) {
    int mv = __builtin_amdgcn_update_dpp(0, __float_as_int(v), CTRL, 0xf, 0xf, true);
    return v + __int_as_float(mv);
}
__device__ __forceinline__ float rdl63(float p) {
    return __int_as_float(__builtin_amdgcn_readlane(__float_as_int(p), 63));
}

// One wave (64 lanes) per batch element; 4 waves per 256-thread block.
// B=1024 waves = 1 wave/SIMD on MI355X -> wall time = max(per-step issue,
// per-step chain). Body is STAGE-MAJOR (tanh chains overlapped) and the
// elementwise FP32 work is packed as float2 -> v_pk_*_f32 (dual-FP32 VOP3P,
// same issue slots as scalar, 2 ops/lane) to cut issue count.
__global__ __launch_bounds__(256, 1) void rnn_lowrank_kernel(
    const float* __restrict__ u,   // (B, T)
    const float* __restrict__ m,   // (N, 2) row-major
    const float* __restrict__ n,   // (N, 2) row-major
    const float* __restrict__ wi,  // (N,)
    const float* __restrict__ w,   // (N, 1)
    float* __restrict__ z)         // (B, T)
{
    __shared__ float u_lds[4][T_LEN];

    const int wave = threadIdx.x >> 6;
    const int lane = threadIdx.x & 63;
    const int b    = (blockIdx.x << 2) + wave;

    const float dt   = 0.2f;
    const float invN = 1.0f / 256.0f;
    const float c    = 2.8853900817779268f;  // 2*log2(e): track y = c*x

    // ---- stage u row (pre-scaled by dt) into LDS; wave-private, no barrier ----
    {
        const float4* src = reinterpret_cast<const float4*>(u + (size_t)b * T_LEN);
        float4*       dst = reinterpret_cast<float4*>(&u_lds[wave][0]);
#pragma unroll
        for (int k = 0; k < 4; ++k) {
            float4 v = src[lane + (k << 6)];
            v.x *= dt; v.y *= dt; v.z *= dt; v.w *= dt;
            dst[lane + (k << 6)] = v;
        }
    }

    // ---- weights as named f2 pairs (elements {j0,j1} and {j2,j3}) ----
    // Basis: y_{t+1} = A'*(c*m0) + B'*(c*m1) + G'*(c*wi)
    //   A' = 0.8A + a0,  a0 = sum r * n0*(dt/N)
    //   B' = 0.8B + a1,  a1 = sum r * n1*(dt/N)
    //   G' = 0.8G + dt*u_t                      (dt folded at staging)
    //   r  = 1 - 2/(exp2(y)+1) == tanh(x),  z_t = sum r * (w/N)
    const int j0 = lane, j1 = lane + 64, j2 = lane + 128, j3 = lane + 192;
    const float kn = dt * invN;
    const f2 m0_01 = (f2){m[2*j0+0]*c,  m[2*j1+0]*c };
    const f2 m0_23 = (f2){m[2*j2+0]*c,  m[2*j3+0]*c };
    const f2 m1_01 = (f2){m[2*j0+1]*c,  m[2*j1+1]*c };
    const f2 m1_23 = (f2){m[2*j2+1]*c,  m[2*j3+1]*c };
    const f2 wi_01 = (f2){wi[j0]*c,     wi[j1]*c    };
    const f2 wi_23 = (f2){wi[j2]*c,     wi[j3]*c    };
    const f2 n0_01 = (f2){n[2*j0+0]*kn, n[2*j1+0]*kn};
    const f2 n0_23 = (f2){n[2*j2+0]*kn, n[2*j3+0]*kn};
    const f2 n1_01 = (f2){n[2*j0+1]*kn, n[2*j1+1]*kn};
    const f2 n1_23 = (f2){n[2*j2+1]*kn, n[2*j3+1]*kn};
    const f2 w_01  = (f2){w[j0]*invN,   w[j1]*invN  };
    const f2 w_23  = (f2){w[j2]*invN,   w[j3]*invN  };

    float A = 0.0f, B = 0.0f, G = 0.0f;   // uniform coeffs of y in basis
    float a0 = 0.0f, a1 = 0.0f;           // reductions from prev step (r_0 = 0)
    float zbuf = 0.0f;
    float u_cur = u_lds[wave][0];

#pragma unroll 2
    for (int t = 0; t < T_LEN; ++t) {
        // ---- off-chain: next-u prefetch + input path (independent of a0/a1) ----
        float u_next = u_lds[wave][(t + 1) & (T_LEN - 1)];
        G = fmaf(G, 0.8f, u_cur);                 // G_{t+1}
        f2 g01 = sp(G) * wi_01;
        f2 g23 = sp(G) * wi_23;

        // ---- chain head: A',B' from SGPRs a0,a1 ----
        A = fmaf(A, 0.8f, a0);
        B = fmaf(B, 0.8f, a1);

        // ---- two packed y chains: y = pk_fma(A,m0, pk_fma(B,m1, g)) ----
        f2 y01 = __builtin_elementwise_fma(sp(B), m1_01, g01);
        f2 y23 = __builtin_elementwise_fma(sp(B), m1_23, g23);
        y01 = __builtin_elementwise_fma(sp(A), m0_01, y01);
        y23 = __builtin_elementwise_fma(sp(A), m0_23, y23);

        // ---- four exp2 / rcp chains overlapped (scalar trans ops) ----
        f2 ex01, ex23;
        ex01.x = __builtin_amdgcn_exp2f(y01.x);
        ex01.y = __builtin_amdgcn_exp2f(y01.y);
        ex23.x = __builtin_amdgcn_exp2f(y23.x);
        ex23.y = __builtin_amdgcn_exp2f(y23.y);
        f2 d01 = ex01 + sp(1.0f);
        f2 d23 = ex23 + sp(1.0f);
        f2 rc01, rc23;
        rc01.x = __builtin_amdgcn_rcpf(d01.x);
        rc01.y = __builtin_amdgcn_rcpf(d01.y);
        rc23.x = __builtin_amdgcn_rcpf(d23.x);
        rc23.y = __builtin_amdgcn_rcpf(d23.y);
        f2 r01 = __builtin_elementwise_fma(sp(-2.0f), rc01, sp(1.0f));
        f2 r23 = __builtin_elementwise_fma(sp(-2.0f), rc23, sp(1.0f));

        // ---- packed p-accum (01 first, 23 last -> short tail), then combine ----
        f2 q0 = r01 * n0_01, q1 = r01 * n1_01, qz = r01 * w_01;
        q0 = __builtin_elementwise_fma(r23, n0_23, q0);
        q1 = __builtin_elementwise_fma(r23, n1_23, q1);
        qz = __builtin_elementwise_fma(r23, w_23,  qz);
        float p0 = q0.x + q0.y, p1 = q1.x + q1.y, pz = qz.x + qz.y;

        // ---- three interleaved wave64 DPP trees (sum -> lane 63) ----
#define RED3(CTRL)                      \
        p0 = dpp_add_f32<CTRL>(p0);     \
        p1 = dpp_add_f32<CTRL>(p1);     \
        pz = dpp_add_f32<CTRL>(pz);
        RED3(0x111)  // row_shr:1
        RED3(0x112)  // row_shr:2
        RED3(0x114)  // row_shr:4
        RED3(0x118)  // row_shr:8
        RED3(0x142)  // row_bcast:15
        RED3(0x143)  // row_bcast:31
#undef RED3

        a0 = rdl63(p0);
        a1 = rdl63(p1);
        float zs = rdl63(pz);

        // capture z_t on lane (t mod 64); coalesced 64-wide store every 64 steps
        zbuf = (lane == (t & 63)) ? zs : zbuf;
        if ((t & 63) == 63)
            z[(size_t)b * T_LEN + (t - 63) + lane] = zbuf;

        u_cur = u_next;
    }
}

extern "C" void kernel_launch(void* const* d_in, const int* in_sizes, int n_in,
                              void* d_out, int out_size, void* d_ws, size_t ws_size,
                              hipStream_t stream) {
    const float* u  = (const float*)d_in[0];
    const float* m  = (const float*)d_in[1];
    const float* n  = (const float*)d_in[2];
    const float* wi = (const float*)d_in[3];
    const float* w  = (const float*)d_in[4];
    float* z = (float*)d_out;

    dim3 grid(256), block(256);
    hipLaunchKernelGGL(rnn_lowrank_kernel, grid, block, 0, stream, u, m, n, wi, w, z);
}

// Round 7
// 193.049 us; speedup vs baseline: 1.6346x; 1.0602x over previous
//
#include <hip/hip_runtime.h>

#define T_LEN 1024

typedef float f2 __attribute__((ext_vector_type(2)));

__device__ __forceinline__ f2 sp(float x) { return (f2){x, x}; }

__device__ __forceinline__ float rdl63(float p) {
    return __int_as_float(__builtin_amdgcn_readlane(__float_as_int(p), 63));
}

// One DPP reduction level as a single guaranteed v_add_f32_dpp instruction
// (intrinsic update_dpp may split into v_mov_b32_dpp + v_add_f32).
// bound_ctrl:0 => invalid source lanes read 0 (safe for sum).
#define DPP_ADD(P, CTRL)                                                     \
    asm("v_add_f32_dpp %0, %0, %0 " CTRL " row_mask:0xf bank_mask:0xf bound_ctrl:0" \
        : "+v"(P))

// One wave (64 lanes) per batch element; 4 waves per 256-thread block.
// B=1024 waves = 1 wave/SIMD on MI355X -> wall time = per-SIMD issue count
// (chain now shorter than issue). Elementwise math packed as float2
// (v_pk_*_f32 dual-FP32); a0/a1 reduced via 6-level asm DPP trees; the z
// reduction is taken OFF the per-step path: per-lane partials go to a
// wave-private LDS matrix, reduced once per 64 steps with rotated
// (conflict-free) columns and stored coalesced.
__global__ __launch_bounds__(256, 1) void rnn_lowrank_kernel(
    const float* __restrict__ u,   // (B, T)
    const float* __restrict__ m,   // (N, 2) row-major
    const float* __restrict__ n,   // (N, 2) row-major
    const float* __restrict__ wi,  // (N,)
    const float* __restrict__ w,   // (N, 1)
    float* __restrict__ z)         // (B, T)
{
    __shared__ float u_lds[4][T_LEN];      // 16 KB
    __shared__ float zmat[4][64][64];      // 64 KB: [wave][step-in-window][lane]

    const int wave = threadIdx.x >> 6;
    const int lane = threadIdx.x & 63;
    const int b    = (blockIdx.x << 2) + wave;

    const float dt   = 0.2f;
    const float invN = 1.0f / 256.0f;
    const float c    = 2.8853900817779268f;  // 2*log2(e): track y = c*x

    // ---- stage u row (pre-scaled by dt) into LDS; wave-private, no barrier ----
    {
        const float4* src = reinterpret_cast<const float4*>(u + (size_t)b * T_LEN);
        float4*       dst = reinterpret_cast<float4*>(&u_lds[wave][0]);
#pragma unroll
        for (int k = 0; k < 4; ++k) {
            float4 v = src[lane + (k << 6)];
            v.x *= dt; v.y *= dt; v.z *= dt; v.w *= dt;
            dst[lane + (k << 6)] = v;
        }
    }

    // ---- weights as named f2 pairs (elements {j0,j1} and {j2,j3}) ----
    // Basis: y_{t+1} = A'*(c*m0) + B'*(c*m1) + G'*(c*wi)
    //   A' = 0.8A + a0,  a0 = sum r * n0*(dt/N)
    //   B' = 0.8B + a1,  a1 = sum r * n1*(dt/N)
    //   G' = 0.8G + dt*u_t                      (dt folded at staging)
    //   r  = 1 - 2/(exp2(y)+1) == tanh(x),  z_t = sum r * (w/N)
    const int j0 = lane, j1 = lane + 64, j2 = lane + 128, j3 = lane + 192;
    const float kn = dt * invN;
    const f2 m0_01 = (f2){m[2*j0+0]*c,  m[2*j1+0]*c };
    const f2 m0_23 = (f2){m[2*j2+0]*c,  m[2*j3+0]*c };
    const f2 m1_01 = (f2){m[2*j0+1]*c,  m[2*j1+1]*c };
    const f2 m1_23 = (f2){m[2*j2+1]*c,  m[2*j3+1]*c };
    const f2 wi_01 = (f2){wi[j0]*c,     wi[j1]*c    };
    const f2 wi_23 = (f2){wi[j2]*c,     wi[j3]*c    };
    const f2 n0_01 = (f2){n[2*j0+0]*kn, n[2*j1+0]*kn};
    const f2 n0_23 = (f2){n[2*j2+0]*kn, n[2*j3+0]*kn};
    const f2 n1_01 = (f2){n[2*j0+1]*kn, n[2*j1+1]*kn};
    const f2 n1_23 = (f2){n[2*j2+1]*kn, n[2*j3+1]*kn};
    const f2 w_01  = (f2){w[j0]*invN,   w[j1]*invN  };
    const f2 w_23  = (f2){w[j2]*invN,   w[j3]*invN  };

    float A = 0.0f, B = 0.0f, G = 0.0f;   // uniform coeffs of y in basis
    float a0 = 0.0f, a1 = 0.0f;           // reductions from prev step (r_0 = 0)
    float u_cur = u_lds[wave][0];

#pragma unroll 4
    for (int t = 0; t < T_LEN; ++t) {
        // ---- off-chain: next-u prefetch + input path (independent of a0/a1) ----
        float u_next = u_lds[wave][(t + 1) & (T_LEN - 1)];
        G = fmaf(G, 0.8f, u_cur);                 // G_{t+1}
        f2 g01 = sp(G) * wi_01;
        f2 g23 = sp(G) * wi_23;

        // ---- chain head: A',B' from SGPRs a0,a1 ----
        A = fmaf(A, 0.8f, a0);
        B = fmaf(B, 0.8f, a1);

        // ---- two packed y chains: y = pk_fma(A,m0, pk_fma(B,m1, g)) ----
        f2 y01 = __builtin_elementwise_fma(sp(B), m1_01, g01);
        f2 y23 = __builtin_elementwise_fma(sp(B), m1_23, g23);
        y01 = __builtin_elementwise_fma(sp(A), m0_01, y01);
        y23 = __builtin_elementwise_fma(sp(A), m0_23, y23);

        // ---- four exp2 / rcp chains overlapped (scalar trans ops) ----
        f2 ex01, ex23;
        ex01.x = __builtin_amdgcn_exp2f(y01.x);
        ex01.y = __builtin_amdgcn_exp2f(y01.y);
        ex23.x = __builtin_amdgcn_exp2f(y23.x);
        ex23.y = __builtin_amdgcn_exp2f(y23.y);
        f2 d01 = ex01 + sp(1.0f);
        f2 d23 = ex23 + sp(1.0f);
        f2 rc01, rc23;
        rc01.x = __builtin_amdgcn_rcpf(d01.x);
        rc01.y = __builtin_amdgcn_rcpf(d01.y);
        rc23.x = __builtin_amdgcn_rcpf(d23.x);
        rc23.y = __builtin_amdgcn_rcpf(d23.y);
        f2 r01 = __builtin_elementwise_fma(sp(-2.0f), rc01, sp(1.0f));
        f2 r23 = __builtin_elementwise_fma(sp(-2.0f), rc23, sp(1.0f));

        // ---- packed p-accum (01 first, 23 last -> short tail), then combine ----
        f2 q0 = r01 * n0_01, q1 = r01 * n1_01, qz = r01 * w_01;
        q0 = __builtin_elementwise_fma(r23, n0_23, q0);
        q1 = __builtin_elementwise_fma(r23, n1_23, q1);
        qz = __builtin_elementwise_fma(r23, w_23,  qz);
        float p0 = q0.x + q0.y, p1 = q1.x + q1.y;

        // z partial: off the serial path -> LDS matrix (row = step-in-window)
        zmat[wave][t & 63][lane] = qz.x + qz.y;

        // ---- two interleaved 6-level asm DPP trees (sum -> lane 63) ----
        DPP_ADD(p0, "row_shr:1");  DPP_ADD(p1, "row_shr:1");
        DPP_ADD(p0, "row_shr:2");  DPP_ADD(p1, "row_shr:2");
        DPP_ADD(p0, "row_shr:4");  DPP_ADD(p1, "row_shr:4");
        DPP_ADD(p0, "row_shr:8");  DPP_ADD(p1, "row_shr:8");
        DPP_ADD(p0, "row_bcast:15"); DPP_ADD(p1, "row_bcast:15");
        DPP_ADD(p0, "row_bcast:31"); DPP_ADD(p1, "row_bcast:31");

        a0 = rdl63(p0);
        a1 = rdl63(p1);

        // ---- window flush: transpose-reduce zmat, coalesced store ----
        if ((t & 63) == 63) {
            float s0 = 0.0f, s1 = 0.0f, s2 = 0.0f, s3 = 0.0f;
#pragma unroll
            for (int k = 0; k < 64; k += 4) {   // rotated cols: conflict-free
                s0 += zmat[wave][lane][(lane + k + 0) & 63];
                s1 += zmat[wave][lane][(lane + k + 1) & 63];
                s2 += zmat[wave][lane][(lane + k + 2) & 63];
                s3 += zmat[wave][lane][(lane + k + 3) & 63];
            }
            z[(size_t)b * T_LEN + (t - 63) + lane] = (s0 + s1) + (s2 + s3);
        }

        u_cur = u_next;
    }
}

extern "C" void kernel_launch(void* const* d_in, const int* in_sizes, int n_in,
                              void* d_out, int out_size, void* d_ws, size_t ws_size,
                              hipStream_t stream) {
    const float* u  = (const float*)d_in[0];
    const float* m  = (const float*)d_in[1];
    const float* n  = (const float*)d_in[2];
    const float* wi = (const float*)d_in[3];
    const float* w  = (const float*)d_in[4];
    float* z = (float*)d_out;

    dim3 grid(256), block(256);
    hipLaunchKernelGGL(rnn_lowrank_kernel, grid, block, 0, stream, u, m, n, wi, w, z);
}